// Round 7
// baseline (482.440 us; speedup 1.0000x reference)
//
#include <hip/hip_runtime.h>
#include <hip/hip_fp16.h>

#define HEADS 2
#define DD 128
#define FF 16
#define HD 256  // HEADS*DD
#define NEG_SLOPE 0.2f
#define EPSV 1e-16f

static __device__ __forceinline__ float rdlanef(float v, int i){
  return __uint_as_float(__builtin_amdgcn_readlane(__float_as_uint(v), i));
}
static __device__ __forceinline__ int rdlanei(int v, int i){
  return __builtin_amdgcn_readlane(v, i);
}

// ---------------- CSR build ----------------
__global__ void k_hist(const int* __restrict__ dst, int* __restrict__ counts, int E, int Etot){
  int e = blockIdx.x*256 + threadIdx.x;
  if (e >= Etot) return;
  int dn = (e < E) ? dst[e] : (e - E);
  atomicAdd(&counts[dn], 1);
}

__global__ __launch_bounds__(1024) void k_scan(const int* __restrict__ counts, int* __restrict__ starts,
                       int* __restrict__ cursor, int N, int Etot){
  __shared__ int s[1024];
  int t = threadIdx.x;
  const int CHN = (N + 1023) / 1024;
  int lo = t*CHN, hi = min(lo+CHN, N);
  int loc = 0;
  for (int i = lo; i < hi; i++) loc += counts[i];
  s[t] = loc;
  __syncthreads();
  for (int off = 1; off < 1024; off <<= 1){
    int v = (t >= off) ? s[t-off] : 0;
    __syncthreads();
    s[t] += v;
    __syncthreads();
  }
  int run = (t == 0) ? 0 : s[t-1];
  for (int i = lo; i < hi; i++){
    starts[i] = run; cursor[i] = run; run += counts[i];
  }
  if (t == 0) starts[N] = Etot;
}

__global__ void k_scatter(const int* __restrict__ dst, int* __restrict__ cursor,
                          int* __restrict__ eids, int E, int Etot){
  int e = blockIdx.x*256 + threadIdx.x;
  if (e >= Etot) return;
  int dn = (e < E) ? dst[e] : (e - E);
  int pos = atomicAdd(&cursor[dn], 1);
  eids[pos] = e;
}

// Build CSR-ordered src + attr (layer-invariant)
__global__ void k_gather_csr(const int* __restrict__ eids, const int* __restrict__ src,
                             const float* __restrict__ eattr,
                             int* __restrict__ srcC, float* __restrict__ attrC, int E, int Etot){
  int i = blockIdx.x*256 + threadIdx.x;
  if (i >= Etot) return;
  int eid = eids[i];
  srcC[i] = (eid < E) ? src[eid] : (eid - E);
  float4* o = (float4*)&attrC[(size_t)i*FF];
  if (eid < E){
    const float4* in = (const float4*)&eattr[(size_t)eid*FF];
    o[0]=in[0]; o[1]=in[1]; o[2]=in[2]; o[3]=in[3];
  } else {
    float4 z = make_float4(0.f,0.f,0.f,0.f);
    o[0]=z; o[1]=z; o[2]=z; o[3]=z;
  }
}

// c5[l][h*16+f] = sum_d att_j[h,d]*ew[h*128+d, f];  c5[l][32+h] = att_j[h]·eb[h]
__global__ void k_prec5(const float* __restrict__ atts, const float* __restrict__ edge_ws,
                        const float* __restrict__ edge_bs, float* __restrict__ c5){
  int l = blockIdx.x;
  int t = threadIdx.x;
  const float* att = atts    + (size_t)l*HEADS*2*DD;
  const float* ew  = edge_ws + (size_t)l*HD*FF;
  const float* eb  = edge_bs + (size_t)l*HD;
  float* c = c5 + (size_t)l*34;
  if (t < 32){
    int h = t >> 4, f = t & 15;
    float acc = 0.f;
    for (int d = 0; d < DD; d++) acc += att[h*2*DD + DD + d]*ew[(size_t)(h*DD+d)*FF + f];
    c[h*FF + f] = acc;
  } else if (t < 34){
    int h = t - 32;
    float acc = 0.f;
    for (int d = 0; d < DD; d++) acc += att[h*2*DD + DD + d]*eb[h*DD + d];
    c[32 + h] = acc;
  }
}

// xw[N,256] (fp16) = h[N,128] @ W[128,256]; fused s[n][4] = {si_h0, si_h1, sj_h0, sj_h1}
// tile: 16 rows x 256 cols; thread: 4 rows x 4 cols (float4)
__global__ __launch_bounds__(256) void k_gemm_xw(const float* __restrict__ h, const float* __restrict__ W,
                         const float* __restrict__ att, __half* __restrict__ xwh,
                         float* __restrict__ sbuf, int N){
  __shared__ float sx[16][DD];
  int r0 = blockIdx.x * 16;
  int rows = min(16, N - r0);
  int t = threadIdx.x;
  for (int idx = t; idx < 16*(DD/4); idx += 256){
    int r = idx >> 5, kq = idx & 31;
    float4 v = make_float4(0.f,0.f,0.f,0.f);
    if (r < rows) v = *(const float4*)&h[(size_t)(r0+r)*DD + kq*4];
    *(float4*)&sx[r][kq*4] = v;
  }
  __syncthreads();
  int tx = t & 63, ty = t >> 6;
  int c0 = tx*4;
  float4 acc[4];
  #pragma unroll
  for (int r = 0; r < 4; r++) acc[r] = make_float4(0.f,0.f,0.f,0.f);
  #pragma unroll 4
  for (int kq = 0; kq < 32; kq++){
    float4 w0 = *(const float4*)&W[(size_t)(kq*4+0)*HD + c0];
    float4 w1 = *(const float4*)&W[(size_t)(kq*4+1)*HD + c0];
    float4 w2 = *(const float4*)&W[(size_t)(kq*4+2)*HD + c0];
    float4 w3 = *(const float4*)&W[(size_t)(kq*4+3)*HD + c0];
    #pragma unroll
    for (int r = 0; r < 4; r++){
      float4 hv = *(const float4*)&sx[ty*4+r][kq*4];
      acc[r].x = fmaf(hv.x, w0.x, acc[r].x); acc[r].y = fmaf(hv.x, w0.y, acc[r].y);
      acc[r].z = fmaf(hv.x, w0.z, acc[r].z); acc[r].w = fmaf(hv.x, w0.w, acc[r].w);
      acc[r].x = fmaf(hv.y, w1.x, acc[r].x); acc[r].y = fmaf(hv.y, w1.y, acc[r].y);
      acc[r].z = fmaf(hv.y, w1.z, acc[r].z); acc[r].w = fmaf(hv.y, w1.w, acc[r].w);
      acc[r].x = fmaf(hv.z, w2.x, acc[r].x); acc[r].y = fmaf(hv.z, w2.y, acc[r].y);
      acc[r].z = fmaf(hv.z, w2.z, acc[r].z); acc[r].w = fmaf(hv.z, w2.w, acc[r].w);
      acc[r].x = fmaf(hv.w, w3.x, acc[r].x); acc[r].y = fmaf(hv.w, w3.y, acc[r].y);
      acc[r].z = fmaf(hv.w, w3.z, acc[r].z); acc[r].w = fmaf(hv.w, w3.w, acc[r].w);
    }
  }
  #pragma unroll
  for (int r = 0; r < 4; r++){
    if (ty*4+r < rows){
      __half2 p0 = __floats2half2_rn(acc[r].x, acc[r].y);
      __half2 p1 = __floats2half2_rn(acc[r].z, acc[r].w);
      uint2 pk;
      pk.x = *(unsigned*)&p0;
      pk.y = *(unsigned*)&p1;
      *(uint2*)&xwh[(size_t)(r0+ty*4+r)*HD + c0] = pk;
    }
  }
  // fused per-node attention scalars (from fp32 acc, full precision)
  int hsel = tx >> 5;
  int cm = c0 & 127;
  float4 ai = *(const float4*)&att[hsel*2*DD + cm];
  float4 aj = *(const float4*)&att[hsel*2*DD + DD + cm];
  #pragma unroll
  for (int r = 0; r < 4; r++){
    float pi = acc[r].x*ai.x + acc[r].y*ai.y + acc[r].z*ai.z + acc[r].w*ai.w;
    float pj = acc[r].x*aj.x + acc[r].y*aj.y + acc[r].z*aj.z + acc[r].w*aj.w;
    #pragma unroll
    for (int off = 16; off; off >>= 1){
      pi += __shfl_xor(pi, off);
      pj += __shfl_xor(pj, off);
    }
    int row = ty*4 + r;
    if ((tx & 31) == 0 && row < rows){
      sbuf[(size_t)(r0+row)*4 + 0 + hsel] = pi;
      sbuf[(size_t)(r0+row)*4 + 2 + hsel] = pj;
    }
  }
}

static __device__ __forceinline__ void alpha_edge(int idx, const int* __restrict__ srcC,
    const float* __restrict__ s, const float* __restrict__ attrC,
    const float* cf0, const float* cf1, float c32, float c33,
    float sdx, float sdy, float& a0, float& a1, int& msrc){
  msrc = srcC[idx];
  float2 sj = *(const float2*)&s[(size_t)msrc*4+2];
  const float4* ap = (const float4*)&attrC[(size_t)idx*FF];
  float4 t0=ap[0], t1=ap[1], t2=ap[2], t3=ap[3];
  float x0 = sdx + sj.x + c32;
  float x1 = sdy + sj.y + c33;
  x0 = fmaf(t0.x,cf0[0],x0); x0 = fmaf(t0.y,cf0[1],x0); x0 = fmaf(t0.z,cf0[2],x0); x0 = fmaf(t0.w,cf0[3],x0);
  x0 = fmaf(t1.x,cf0[4],x0); x0 = fmaf(t1.y,cf0[5],x0); x0 = fmaf(t1.z,cf0[6],x0); x0 = fmaf(t1.w,cf0[7],x0);
  x0 = fmaf(t2.x,cf0[8],x0); x0 = fmaf(t2.y,cf0[9],x0); x0 = fmaf(t2.z,cf0[10],x0); x0 = fmaf(t2.w,cf0[11],x0);
  x0 = fmaf(t3.x,cf0[12],x0); x0 = fmaf(t3.y,cf0[13],x0); x0 = fmaf(t3.z,cf0[14],x0); x0 = fmaf(t3.w,cf0[15],x0);
  x1 = fmaf(t0.x,cf1[0],x1); x1 = fmaf(t0.y,cf1[1],x1); x1 = fmaf(t0.z,cf1[2],x1); x1 = fmaf(t0.w,cf1[3],x1);
  x1 = fmaf(t1.x,cf1[4],x1); x1 = fmaf(t1.y,cf1[5],x1); x1 = fmaf(t1.z,cf1[6],x1); x1 = fmaf(t1.w,cf1[7],x1);
  x1 = fmaf(t2.x,cf1[8],x1); x1 = fmaf(t2.y,cf1[9],x1); x1 = fmaf(t2.z,cf1[10],x1); x1 = fmaf(t2.w,cf1[11],x1);
  x1 = fmaf(t3.x,cf1[12],x1); x1 = fmaf(t3.y,cf1[13],x1); x1 = fmaf(t3.z,cf1[14],x1); x1 = fmaf(t3.w,cf1[15],x1);
  a0 = (x0 > 0.f) ? x0 : NEG_SLOPE*x0;
  a1 = (x1 > 0.f) ? x1 : NEG_SLOPE*x1;
}

// wave-per-node, single pass. Edge-pairing: lanes 0-31 accumulate even edges,
// lanes 32-63 odd edges; each lane gathers 16B (8 fp16 cols) per pair -> half
// the latency exposures of the 8B/lane scheme. Parity partials merged at end
// via shfl_xor(32) (each half REALLY holds half the edges here, cf. R4 bug).
__global__ __launch_bounds__(256) void k_aggr(const int* __restrict__ starts, const int* __restrict__ srcC,
                      const float* __restrict__ attrC, const float* __restrict__ s,
                      const float* __restrict__ c, const __half* __restrict__ xwh,
                      const float* __restrict__ ew, const float* __restrict__ eb,
                      const float* __restrict__ bias, float* __restrict__ out, int N, int relu){
  int lane = threadIdx.x & 63, wid = threadIdx.x >> 6;
  int n = blockIdx.x*4 + wid;
  if (n >= N) return;

  float cf0[FF], cf1[FF];
  #pragma unroll
  for (int f = 0; f < FF; f++){ cf0[f] = c[f]; cf1[f] = c[FF+f]; }
  float c32 = c[32], c33 = c[33];
  float sdx = s[(size_t)n*4+0], sdy = s[(size_t)n*4+1];
  int st = starts[n];
  int deg = starts[n+1] - st;

  int gpar = lane >> 5;     // edge parity this lane accumulates
  int l31  = lane & 31;
  int hh   = l31 >> 4;      // head of my 8 columns (== tacc head h2)
  int c8   = l31 * 8;       // starting column (8 fp16 = 16B)
  int f2   = lane & 15;

  float acc[8];
  #pragma unroll
  for (int k = 0; k < 8; k++) acc[k] = 0.f;
  float ls0 = 0.f, ls1 = 0.f, tacc = 0.f;

  for (int base = 0; base < deg; base += 64){
    int cnt = min(64, deg - base);
    float e0 = 0.f, e1 = 0.f; int msrc = 0;
    if (lane < cnt){
      float a0, a1;
      alpha_edge(st+base+lane, srcC, s, attrC, cf0, cf1, c32, c33, sdx, sdy, a0, a1, msrc);
      e0 = expf(a0); e1 = expf(a1);
      ls0 += e0; ls1 += e1;
    }
    const float* abase = &attrC[(size_t)(st+base)*FF];
    #pragma unroll 4
    for (int i = 0; i < cnt; i += 2){
      int i1 = (i+1 < cnt) ? (i+1) : i;          // clamp odd tail
      int   sA  = rdlanei(msrc, i);
      int   sB  = rdlanei(msrc, i1);
      float wa0 = rdlanef(e0, i),  wa1 = rdlanef(e1, i);
      float wb0 = rdlanef(e0, i1), wb1 = rdlanef(e1, i1);
      int   sn = gpar ? sB : sA;
      float w0 = gpar ? wb0 : wa0;
      float w1 = gpar ? wb1 : wa1;
      float ws = hh ? w1 : w0;
      if (gpar && (i+1 >= cnt)) ws = 0.f;        // clamped edge contributes 0
      int ec = gpar ? i1 : i;
      uint4 u = *(const uint4*)&xwh[(size_t)sn*HD + c8];
      __half2 q0 = *(__half2*)&u.x, q1 = *(__half2*)&u.y;
      __half2 q2 = *(__half2*)&u.z, q3 = *(__half2*)&u.w;
      float2 v0 = __half22float2(q0), v1 = __half22float2(q1);
      float2 v2 = __half22float2(q2), v3 = __half22float2(q3);
      acc[0] = fmaf(ws, v0.x, acc[0]); acc[1] = fmaf(ws, v0.y, acc[1]);
      acc[2] = fmaf(ws, v1.x, acc[2]); acc[3] = fmaf(ws, v1.y, acc[3]);
      acc[4] = fmaf(ws, v2.x, acc[4]); acc[5] = fmaf(ws, v2.y, acc[5]);
      acc[6] = fmaf(ws, v3.x, acc[6]); acc[7] = fmaf(ws, v3.y, acc[7]);
      tacc = fmaf(ws, abase[(size_t)ec*FF + f2], tacc);
    }
  }

  // merge parity halves (required: each half holds half the edges)
  #pragma unroll
  for (int k = 0; k < 8; k++) acc[k] += __shfl_xor(acc[k], 32);
  tacc += __shfl_xor(tacc, 32);
  #pragma unroll
  for (int off = 32; off; off >>= 1){
    ls0 += __shfl_xor(ls0, off);
    ls1 += __shfl_xor(ls1, off);
  }

  if (lane < 32){
    // lane (hh*16+f2) holds complete t[h][f] after merge
    float th[FF];
    #pragma unroll
    for (int f = 0; f < FF; f++) th[f] = __shfl(tacc, hh*FF + f);
    float di = 1.f/((hh ? ls1 : ls0) + EPSV);
    float4 eb0 = *(const float4*)&eb[c8];
    float4 eb1 = *(const float4*)&eb[c8+4];
    float r[8];
    #pragma unroll
    for (int k = 0; k < 8; k++){
      const float4* er = (const float4*)&ew[(size_t)(c8+k)*FF];
      float4 g0 = er[0], g1 = er[1], g2 = er[2], g3 = er[3];
      float v = th[0]*g0.x + th[1]*g0.y + th[2]*g0.z + th[3]*g0.w;
      v = fmaf(th[4],  g1.x, v); v = fmaf(th[5],  g1.y, v); v = fmaf(th[6],  g1.z, v); v = fmaf(th[7],  g1.w, v);
      v = fmaf(th[8],  g2.x, v); v = fmaf(th[9],  g2.y, v); v = fmaf(th[10], g2.z, v); v = fmaf(th[11], g2.w, v);
      v = fmaf(th[12], g3.x, v); v = fmaf(th[13], g3.y, v); v = fmaf(th[14], g3.z, v); v = fmaf(th[15], g3.w, v);
      float ebk = (k < 4) ? ((const float*)&eb0)[k] : ((const float*)&eb1)[k-4];
      r[k] = di*(acc[k] + v) + ebk;
    }
    // head mean: lane l (<16, head0 cols d=l*8+k) pairs with lane l+16 (head1 cols d+128)
    float o[8];
    #pragma unroll
    for (int k = 0; k < 8; k++){
      float pr = __shfl_xor(r[k], 16);
      o[k] = 0.5f*(r[k] + pr);
    }
    if (lane < 16){
      float4 b0 = *(const float4*)&bias[c8];
      float4 b1 = *(const float4*)&bias[c8+4];
      float4 w0 = make_float4(o[0]+b0.x, o[1]+b0.y, o[2]+b0.z, o[3]+b0.w);
      float4 w1 = make_float4(o[4]+b1.x, o[5]+b1.y, o[6]+b1.z, o[7]+b1.w);
      if (relu){
        w0.x=fmaxf(w0.x,0.f); w0.y=fmaxf(w0.y,0.f); w0.z=fmaxf(w0.z,0.f); w0.w=fmaxf(w0.w,0.f);
        w1.x=fmaxf(w1.x,0.f); w1.y=fmaxf(w1.y,0.f); w1.z=fmaxf(w1.z,0.f); w1.w=fmaxf(w1.w,0.f);
      }
      *(float4*)&out[(size_t)n*DD + c8]     = w0;
      *(float4*)&out[(size_t)n*DD + c8 + 4] = w1;
    }
  }
}

extern "C" void kernel_launch(void* const* d_in, const int* in_sizes, int n_in,
                              void* d_out, int out_size, void* d_ws, size_t ws_size,
                              hipStream_t stream){
  const float* x       = (const float*)d_in[0];
  const int*   eidx    = (const int*)d_in[1];
  const float* eattr   = (const float*)d_in[2];
  const float* weights = (const float*)d_in[3];
  const float* atts    = (const float*)d_in[4];
  const float* biases  = (const float*)d_in[5];
  const float* edge_ws = (const float*)d_in[6];
  const float* edge_bs = (const float*)d_in[7];
  const int N = in_sizes[0]/DD;
  const int E = in_sizes[1]/2;
  const int Etot = E + N;
  const int* src = eidx;
  const int* dst = eidx + E;

  char* p = (char*)d_ws;
  auto alloc = [&](size_t bytes){ void* r = (void*)p; p += (bytes + 255) & ~(size_t)255; return r; };
  float*    hA     = (float*)alloc((size_t)N*DD*4);
  float*    hB     = (float*)alloc((size_t)N*DD*4);
  __half*   xwh    = (__half*)alloc((size_t)N*HD*2);
  float*    sbuf   = (float*)alloc((size_t)N*4*4);      // aliases counts/cursor during build
  int*      starts = (int*)alloc((size_t)(N+1)*4);
  int*      srcC   = (int*)alloc((size_t)Etot*4);
  int*      eids   = (int*)alloc((size_t)Etot*4);
  float*    attrC  = (float*)alloc((size_t)Etot*FF*4);
  float*    c5     = (float*)alloc(5*34*4);

  int* counts = (int*)sbuf;                       // build-phase alias
  int* cursor = (int*)((char*)sbuf + 65536);      // build-phase alias

  const int ebl = (Etot + 255)/256;

  // CSR build over dst (layer-invariant)
  hipMemsetAsync(counts, 0, (size_t)N*4, stream);
  k_hist<<<ebl, 256, 0, stream>>>(dst, counts, E, Etot);
  k_scan<<<1, 1024, 0, stream>>>(counts, starts, cursor, N, Etot);
  k_scatter<<<ebl, 256, 0, stream>>>(dst, cursor, eids, E, Etot);
  k_gather_csr<<<ebl, 256, 0, stream>>>(eids, src, eattr, srcC, attrC, E, Etot);
  k_prec5<<<5, 64, 0, stream>>>(atts, edge_ws, edge_bs, c5);

  const float* hin = x;
  for (int l = 0; l < 5; l++){
    const float* W   = weights + (size_t)l*DD*HD;
    const float* att = atts    + (size_t)l*HEADS*2*DD;
    const float* b   = biases  + (size_t)l*DD;
    const float* ew  = edge_ws + (size_t)l*HD*FF;
    const float* eb  = edge_bs + (size_t)l*HD;
    const float* c   = c5 + (size_t)l*34;
    float* hout = (l == 4) ? (float*)d_out : ((l & 1) ? hB : hA);

    k_gemm_xw<<<(N+15)/16, 256, 0, stream>>>(hin, W, att, xwh, sbuf, N);
    k_aggr<<<(N+3)/4, 256, 0, stream>>>(starts, srcC, attrC, sbuf, c, xwh, ew, eb, b, hout, N, (l < 4) ? 1 : 0);

    hin = hout;
  }
}

// Round 8
// 399.753 us; speedup vs baseline: 1.2068x; 1.2068x over previous
//
#include <hip/hip_runtime.h>
#include <hip/hip_fp16.h>

#define HEADS 2
#define DD 128
#define FF 16
#define HD 256  // HEADS*DD
#define NEG_SLOPE 0.2f
#define EPSV 1e-16f

static __device__ __forceinline__ float rdlanef(float v, int i){
  return __uint_as_float(__builtin_amdgcn_readlane(__float_as_uint(v), i));
}
static __device__ __forceinline__ int rdlanei(int v, int i){
  return __builtin_amdgcn_readlane(v, i);
}
static __device__ __forceinline__ float4 h4f(uint2 u){
  __half2 h0 = *(__half2*)&u.x;
  __half2 h1 = *(__half2*)&u.y;
  float2 f0 = __half22float2(h0);
  float2 f1 = __half22float2(h1);
  return make_float4(f0.x, f0.y, f1.x, f1.y);
}

// ---------------- CSR build ----------------
__global__ void k_hist(const int* __restrict__ dst, int* __restrict__ counts, int E, int Etot){
  int e = blockIdx.x*256 + threadIdx.x;
  if (e >= Etot) return;
  int dn = (e < E) ? dst[e] : (e - E);
  atomicAdd(&counts[dn], 1);
}

__global__ __launch_bounds__(1024) void k_scan(const int* __restrict__ counts, int* __restrict__ starts,
                       int* __restrict__ cursor, int N, int Etot){
  __shared__ int s[1024];
  int t = threadIdx.x;
  const int CHN = (N + 1023) / 1024;
  int lo = t*CHN, hi = min(lo+CHN, N);
  int loc = 0;
  for (int i = lo; i < hi; i++) loc += counts[i];
  s[t] = loc;
  __syncthreads();
  for (int off = 1; off < 1024; off <<= 1){
    int v = (t >= off) ? s[t-off] : 0;
    __syncthreads();
    s[t] += v;
    __syncthreads();
  }
  int run = (t == 0) ? 0 : s[t-1];
  for (int i = lo; i < hi; i++){
    starts[i] = run; cursor[i] = run; run += counts[i];
  }
  if (t == 0) starts[N] = Etot;
}

__global__ void k_scatter(const int* __restrict__ dst, int* __restrict__ cursor,
                          int* __restrict__ eids, int E, int Etot){
  int e = blockIdx.x*256 + threadIdx.x;
  if (e >= Etot) return;
  int dn = (e < E) ? dst[e] : (e - E);
  int pos = atomicAdd(&cursor[dn], 1);
  eids[pos] = e;
}

// Build CSR-ordered src + attr (layer-invariant)
__global__ void k_gather_csr(const int* __restrict__ eids, const int* __restrict__ src,
                             const float* __restrict__ eattr,
                             int* __restrict__ srcC, float* __restrict__ attrC, int E, int Etot){
  int i = blockIdx.x*256 + threadIdx.x;
  if (i >= Etot) return;
  int eid = eids[i];
  srcC[i] = (eid < E) ? src[eid] : (eid - E);
  float4* o = (float4*)&attrC[(size_t)i*FF];
  if (eid < E){
    const float4* in = (const float4*)&eattr[(size_t)eid*FF];
    o[0]=in[0]; o[1]=in[1]; o[2]=in[2]; o[3]=in[3];
  } else {
    float4 z = make_float4(0.f,0.f,0.f,0.f);
    o[0]=z; o[1]=z; o[2]=z; o[3]=z;
  }
}

// c5[l][h*16+f] = sum_d att_j[h,d]*ew[h*128+d, f];  c5[l][32+h] = att_j[h]·eb[h]
__global__ void k_prec5(const float* __restrict__ atts, const float* __restrict__ edge_ws,
                        const float* __restrict__ edge_bs, float* __restrict__ c5){
  int l = blockIdx.x;
  int t = threadIdx.x;
  const float* att = atts    + (size_t)l*HEADS*2*DD;
  const float* ew  = edge_ws + (size_t)l*HD*FF;
  const float* eb  = edge_bs + (size_t)l*HD;
  float* c = c5 + (size_t)l*34;
  if (t < 32){
    int h = t >> 4, f = t & 15;
    float acc = 0.f;
    for (int d = 0; d < DD; d++) acc += att[h*2*DD + DD + d]*ew[(size_t)(h*DD+d)*FF + f];
    c[h*FF + f] = acc;
  } else if (t < 34){
    int h = t - 32;
    float acc = 0.f;
    for (int d = 0; d < DD; d++) acc += att[h*2*DD + DD + d]*eb[h*DD + d];
    c[32 + h] = acc;
  }
}

// xw[N,256] (fp16) = h[N,128] @ W[128,256]; fused s[n][4] = {si_h0, si_h1, sj_h0, sj_h1}
__global__ __launch_bounds__(256) void k_gemm_xw(const float* __restrict__ h, const float* __restrict__ W,
                         const float* __restrict__ att, __half* __restrict__ xwh,
                         float* __restrict__ sbuf, int N){
  __shared__ float sx[16][DD];
  int r0 = blockIdx.x * 16;
  int rows = min(16, N - r0);
  int t = threadIdx.x;
  for (int idx = t; idx < 16*(DD/4); idx += 256){
    int r = idx >> 5, kq = idx & 31;
    float4 v = make_float4(0.f,0.f,0.f,0.f);
    if (r < rows) v = *(const float4*)&h[(size_t)(r0+r)*DD + kq*4];
    *(float4*)&sx[r][kq*4] = v;
  }
  __syncthreads();
  int tx = t & 63, ty = t >> 6;
  int c0 = tx*4;
  float4 acc[4];
  #pragma unroll
  for (int r = 0; r < 4; r++) acc[r] = make_float4(0.f,0.f,0.f,0.f);
  #pragma unroll 4
  for (int kq = 0; kq < 32; kq++){
    float4 w0 = *(const float4*)&W[(size_t)(kq*4+0)*HD + c0];
    float4 w1 = *(const float4*)&W[(size_t)(kq*4+1)*HD + c0];
    float4 w2 = *(const float4*)&W[(size_t)(kq*4+2)*HD + c0];
    float4 w3 = *(const float4*)&W[(size_t)(kq*4+3)*HD + c0];
    #pragma unroll
    for (int r = 0; r < 4; r++){
      float4 hv = *(const float4*)&sx[ty*4+r][kq*4];
      acc[r].x = fmaf(hv.x, w0.x, acc[r].x); acc[r].y = fmaf(hv.x, w0.y, acc[r].y);
      acc[r].z = fmaf(hv.x, w0.z, acc[r].z); acc[r].w = fmaf(hv.x, w0.w, acc[r].w);
      acc[r].x = fmaf(hv.y, w1.x, acc[r].x); acc[r].y = fmaf(hv.y, w1.y, acc[r].y);
      acc[r].z = fmaf(hv.y, w1.z, acc[r].z); acc[r].w = fmaf(hv.y, w1.w, acc[r].w);
      acc[r].x = fmaf(hv.z, w2.x, acc[r].x); acc[r].y = fmaf(hv.z, w2.y, acc[r].y);
      acc[r].z = fmaf(hv.z, w2.z, acc[r].z); acc[r].w = fmaf(hv.z, w2.w, acc[r].w);
      acc[r].x = fmaf(hv.w, w3.x, acc[r].x); acc[r].y = fmaf(hv.w, w3.y, acc[r].y);
      acc[r].z = fmaf(hv.w, w3.z, acc[r].z); acc[r].w = fmaf(hv.w, w3.w, acc[r].w);
    }
  }
  #pragma unroll
  for (int r = 0; r < 4; r++){
    if (ty*4+r < rows){
      __half2 p0 = __floats2half2_rn(acc[r].x, acc[r].y);
      __half2 p1 = __floats2half2_rn(acc[r].z, acc[r].w);
      uint2 pk;
      pk.x = *(unsigned*)&p0;
      pk.y = *(unsigned*)&p1;
      *(uint2*)&xwh[(size_t)(r0+ty*4+r)*HD + c0] = pk;
    }
  }
  // fused per-node attention scalars (from fp32 acc, full precision)
  int hsel = tx >> 5;
  int cm = c0 & 127;
  float4 ai = *(const float4*)&att[hsel*2*DD + cm];
  float4 aj = *(const float4*)&att[hsel*2*DD + DD + cm];
  #pragma unroll
  for (int r = 0; r < 4; r++){
    float pi = acc[r].x*ai.x + acc[r].y*ai.y + acc[r].z*ai.z + acc[r].w*ai.w;
    float pj = acc[r].x*aj.x + acc[r].y*aj.y + acc[r].z*aj.z + acc[r].w*aj.w;
    #pragma unroll
    for (int off = 16; off; off >>= 1){
      pi += __shfl_xor(pi, off);
      pj += __shfl_xor(pj, off);
    }
    int row = ty*4 + r;
    if ((tx & 31) == 0 && row < rows){
      sbuf[(size_t)(r0+row)*4 + 0 + hsel] = pi;
      sbuf[(size_t)(r0+row)*4 + 2 + hsel] = pj;
    }
  }
}

static __device__ __forceinline__ void alpha_edge(int idx, const int* __restrict__ srcC,
    const float* __restrict__ s, const float* __restrict__ attrC,
    const float* cf0, const float* cf1, float c32, float c33,
    float sdx, float sdy, float& a0, float& a1, int& msrc){
  msrc = srcC[idx];
  float2 sj = *(const float2*)&s[(size_t)msrc*4+2];
  const float4* ap = (const float4*)&attrC[(size_t)idx*FF];
  float4 t0=ap[0], t1=ap[1], t2=ap[2], t3=ap[3];
  float x0 = sdx + sj.x + c32;
  float x1 = sdy + sj.y + c33;
  x0 = fmaf(t0.x,cf0[0],x0); x0 = fmaf(t0.y,cf0[1],x0); x0 = fmaf(t0.z,cf0[2],x0); x0 = fmaf(t0.w,cf0[3],x0);
  x0 = fmaf(t1.x,cf0[4],x0); x0 = fmaf(t1.y,cf0[5],x0); x0 = fmaf(t1.z,cf0[6],x0); x0 = fmaf(t1.w,cf0[7],x0);
  x0 = fmaf(t2.x,cf0[8],x0); x0 = fmaf(t2.y,cf0[9],x0); x0 = fmaf(t2.z,cf0[10],x0); x0 = fmaf(t2.w,cf0[11],x0);
  x0 = fmaf(t3.x,cf0[12],x0); x0 = fmaf(t3.y,cf0[13],x0); x0 = fmaf(t3.z,cf0[14],x0); x0 = fmaf(t3.w,cf0[15],x0);
  x1 = fmaf(t0.x,cf1[0],x1); x1 = fmaf(t0.y,cf1[1],x1); x1 = fmaf(t0.z,cf1[2],x1); x1 = fmaf(t0.w,cf1[3],x1);
  x1 = fmaf(t1.x,cf1[4],x1); x1 = fmaf(t1.y,cf1[5],x1); x1 = fmaf(t1.z,cf1[6],x1); x1 = fmaf(t1.w,cf1[7],x1);
  x1 = fmaf(t2.x,cf1[8],x1); x1 = fmaf(t2.y,cf1[9],x1); x1 = fmaf(t2.z,cf1[10],x1); x1 = fmaf(t2.w,cf1[11],x1);
  x1 = fmaf(t3.x,cf1[12],x1); x1 = fmaf(t3.y,cf1[13],x1); x1 = fmaf(t3.z,cf1[14],x1); x1 = fmaf(t3.w,cf1[15],x1);
  a0 = (x0 > 0.f) ? x0 : NEG_SLOPE*x0;
  a1 = (x1 > 0.f) ? x1 : NEG_SLOPE*x1;
}

// wave-per-node, single pass, 8-deep batched gathers for MLP.
// Lane owns 4 cols (uint2 fp16 = 8B/edge); all 64 lanes cover the 256-col row.
#define BB 8
__global__ __launch_bounds__(256) void k_aggr(const int* __restrict__ starts, const int* __restrict__ srcC,
                      const float* __restrict__ attrC, const float* __restrict__ s,
                      const float* __restrict__ c, const __half* __restrict__ xwh,
                      const float* __restrict__ ew, const float* __restrict__ eb,
                      const float* __restrict__ bias, float* __restrict__ out, int N, int relu){
  int lane = threadIdx.x & 63, wid = threadIdx.x >> 6;
  int n = blockIdx.x*4 + wid;
  if (n >= N) return;

  float cf0[FF], cf1[FF];
  #pragma unroll
  for (int f = 0; f < FF; f++){ cf0[f] = c[f]; cf1[f] = c[FF+f]; }
  float c32 = c[32], c33 = c[33];
  float sdx = s[(size_t)n*4+0], sdy = s[(size_t)n*4+1];
  int st = starts[n];
  int deg = starts[n+1] - st;

  int f2 = lane & 15;
  int h2 = (lane >> 4) & 1;
  int hq = lane >> 5;
  int c0 = lane*4;

  float aAx=0.f, aAy=0.f, aAz=0.f, aAw=0.f;
  float aBx=0.f, aBy=0.f, aBz=0.f, aBw=0.f;
  float ls0=0.f, ls1=0.f, taccA=0.f, taccB=0.f;

  for (int base = 0; base < deg; base += 64){
    int cnt = min(64, deg - base);
    float e0 = 0.f, e1 = 0.f; int msrc = 0;
    if (lane < cnt){
      float a0, a1;
      alpha_edge(st+base+lane, srcC, s, attrC, cf0, cf1, c32, c33, sdx, sdy, a0, a1, msrc);
      e0 = expf(a0); e1 = expf(a1);
      ls0 += e0; ls1 += e1;
    }
    const float* abase = &attrC[(size_t)(st+base)*FF];
    int i = 0;
    for (; i + BB <= cnt; i += BB){
      uint2 u[BB];
      float av[BB];
      // issue all BB gathers + attr reads before any consume (deep MLP)
      #pragma unroll
      for (int k = 0; k < BB; k++){
        int sn = rdlanei(msrc, i+k);
        u[k]  = *(const uint2*)&xwh[(size_t)sn*HD + c0];
        av[k] = abase[(size_t)(i+k)*FF + f2];
      }
      #pragma unroll
      for (int k = 0; k < BB; k++){
        float w0 = rdlanef(e0, i+k);
        float w1 = rdlanef(e1, i+k);
        float ws = hq ? w1 : w0;
        float wt = h2 ? w1 : w0;
        float4 xv = h4f(u[k]);
        if (k & 1){
          aBx = fmaf(ws, xv.x, aBx); aBy = fmaf(ws, xv.y, aBy);
          aBz = fmaf(ws, xv.z, aBz); aBw = fmaf(ws, xv.w, aBw);
          taccB = fmaf(wt, av[k], taccB);
        } else {
          aAx = fmaf(ws, xv.x, aAx); aAy = fmaf(ws, xv.y, aAy);
          aAz = fmaf(ws, xv.z, aAz); aAw = fmaf(ws, xv.w, aAw);
          taccA = fmaf(wt, av[k], taccA);
        }
      }
    }
    for (; i < cnt; i++){
      int sn = rdlanei(msrc, i);
      float w0 = rdlanef(e0, i);
      float w1 = rdlanef(e1, i);
      uint2 u0 = *(const uint2*)&xwh[(size_t)sn*HD + c0];
      float av0 = abase[(size_t)i*FF + f2];
      float ws = hq ? w1 : w0;
      float wt = h2 ? w1 : w0;
      float4 xv = h4f(u0);
      aAx = fmaf(ws, xv.x, aAx); aAy = fmaf(ws, xv.y, aAy);
      aAz = fmaf(ws, xv.z, aAz); aAw = fmaf(ws, xv.w, aAw);
      taccA = fmaf(wt, av0, taccA);
    }
  }
  float ax = aAx + aBx, ay = aAy + aBy, az = aAz + aBz, aw = aAw + aBw;
  float tacc = taccA + taccB;
  #pragma unroll
  for (int off = 32; off; off >>= 1){
    ls0 += __shfl_xor(ls0, off);
    ls1 += __shfl_xor(ls1, off);
  }
  // every lane accumulated tacc over ALL edges: lane (hq*16+f) holds complete t[h][f]

  // epilogue: factored edge-emb + normalize + head-mean + bias
  float th[FF];
  #pragma unroll
  for (int f = 0; f < FF; f++) th[f] = __shfl(tacc, hq*FF + f);
  float embq[4];
  #pragma unroll
  for (int q = 0; q < 4; q++){
    const float4* er = (const float4*)&ew[(size_t)(c0+q)*FF];
    float4 g0 = er[0], g1 = er[1], g2 = er[2], g3 = er[3];
    float v = th[0]*g0.x + th[1]*g0.y + th[2]*g0.z + th[3]*g0.w;
    v = fmaf(th[4],  g1.x, v); v = fmaf(th[5],  g1.y, v); v = fmaf(th[6],  g1.z, v); v = fmaf(th[7],  g1.w, v);
    v = fmaf(th[8],  g2.x, v); v = fmaf(th[9],  g2.y, v); v = fmaf(th[10], g2.z, v); v = fmaf(th[11], g2.w, v);
    v = fmaf(th[12], g3.x, v); v = fmaf(th[13], g3.y, v); v = fmaf(th[14], g3.z, v); v = fmaf(th[15], g3.w, v);
    embq[q] = v;
  }
  float di = 1.f/((hq ? ls1 : ls0) + EPSV);
  float4 ebv = *(const float4*)&eb[c0];
  float r0 = di*(ax + embq[0]) + ebv.x;
  float r1 = di*(ay + embq[1]) + ebv.y;
  float r2 = di*(az + embq[2]) + ebv.z;
  float r3 = di*(aw + embq[3]) + ebv.w;
  float p0 = __shfl_xor(r0, 32);
  float p1 = __shfl_xor(r1, 32);
  float p2 = __shfl_xor(r2, 32);
  float p3 = __shfl_xor(r3, 32);
  if (lane < 32){
    float4 bv = *(const float4*)&bias[c0];
    float4 v;
    v.x = 0.5f*(r0 + p0) + bv.x;
    v.y = 0.5f*(r1 + p1) + bv.y;
    v.z = 0.5f*(r2 + p2) + bv.z;
    v.w = 0.5f*(r3 + p3) + bv.w;
    if (relu){
      v.x = fmaxf(v.x, 0.f); v.y = fmaxf(v.y, 0.f);
      v.z = fmaxf(v.z, 0.f); v.w = fmaxf(v.w, 0.f);
    }
    *(float4*)&out[(size_t)n*DD + c0] = v;
  }
}

extern "C" void kernel_launch(void* const* d_in, const int* in_sizes, int n_in,
                              void* d_out, int out_size, void* d_ws, size_t ws_size,
                              hipStream_t stream){
  const float* x       = (const float*)d_in[0];
  const int*   eidx    = (const int*)d_in[1];
  const float* eattr   = (const float*)d_in[2];
  const float* weights = (const float*)d_in[3];
  const float* atts    = (const float*)d_in[4];
  const float* biases  = (const float*)d_in[5];
  const float* edge_ws = (const float*)d_in[6];
  const float* edge_bs = (const float*)d_in[7];
  const int N = in_sizes[0]/DD;
  const int E = in_sizes[1]/2;
  const int Etot = E + N;
  const int* src = eidx;
  const int* dst = eidx + E;

  char* p = (char*)d_ws;
  auto alloc = [&](size_t bytes){ void* r = (void*)p; p += (bytes + 255) & ~(size_t)255; return r; };
  float*    hA     = (float*)alloc((size_t)N*DD*4);
  float*    hB     = (float*)alloc((size_t)N*DD*4);
  __half*   xwh    = (__half*)alloc((size_t)N*HD*2);
  float*    sbuf   = (float*)alloc((size_t)N*4*4);      // aliases counts/cursor during build
  int*      starts = (int*)alloc((size_t)(N+1)*4);
  int*      srcC   = (int*)alloc((size_t)Etot*4);
  int*      eids   = (int*)alloc((size_t)Etot*4);
  float*    attrC  = (float*)alloc((size_t)Etot*FF*4);
  float*    c5     = (float*)alloc(5*34*4);

  int* counts = (int*)sbuf;                       // build-phase alias
  int* cursor = (int*)((char*)sbuf + 65536);      // build-phase alias

  const int ebl = (Etot + 255)/256;

  // CSR build over dst (layer-invariant)
  hipMemsetAsync(counts, 0, (size_t)N*4, stream);
  k_hist<<<ebl, 256, 0, stream>>>(dst, counts, E, Etot);
  k_scan<<<1, 1024, 0, stream>>>(counts, starts, cursor, N, Etot);
  k_scatter<<<ebl, 256, 0, stream>>>(dst, cursor, eids, E, Etot);
  k_gather_csr<<<ebl, 256, 0, stream>>>(eids, src, eattr, srcC, attrC, E, Etot);
  k_prec5<<<5, 64, 0, stream>>>(atts, edge_ws, edge_bs, c5);

  const float* hin = x;
  for (int l = 0; l < 5; l++){
    const float* W   = weights + (size_t)l*DD*HD;
    const float* att = atts    + (size_t)l*HEADS*2*DD;
    const float* b   = biases  + (size_t)l*DD;
    const float* ew  = edge_ws + (size_t)l*HD*FF;
    const float* eb  = edge_bs + (size_t)l*HD;
    const float* c   = c5 + (size_t)l*34;
    float* hout = (l == 4) ? (float*)d_out : ((l & 1) ? hB : hA);

    k_gemm_xw<<<(N+15)/16, 256, 0, stream>>>(hin, W, att, xwh, sbuf, N);
    k_aggr<<<(N+3)/4, 256, 0, stream>>>(starts, srcC, attrC, sbuf, c, xwh, ew, eb, b, hout, N, (l < 4) ? 1 : 0);

    hin = hout;
  }
}